// Round 1
// baseline (173.168 us; speedup 1.0000x reference)
//
#include <hip/hip_runtime.h>
#include <cfloat>

#define Bn 1024
#define Ln 200
#define En 128
#define An 128
#define Hn 4
#define LP 208   // L padded to 13*16

using f32x4  = __attribute__((ext_vector_type(4))) float;
using bf16x8 = __attribute__((ext_vector_type(8))) short;

__device__ __forceinline__ unsigned short f2bf(float f){
    unsigned u = __builtin_bit_cast(unsigned, f);
    u = (u + 0x7FFFu + ((u >> 16) & 1u)) >> 16;   // RNE
    return (unsigned short)u;
}
__device__ __forceinline__ float bf2f(unsigned short s){
    unsigned u = ((unsigned)s) << 16;
    return __builtin_bit_cast(float, u);
}
__device__ __forceinline__ float tanh_fast(float x){
    x = fminf(fmaxf(x, -12.f), 12.f);
    float e = __expf(2.f * x);
    return 1.f - 2.f / (e + 1.f);
}
// swizzled short-index for a [row][128] bf16 LDS array (256B rows, 16B granule XOR)
__device__ __forceinline__ int swz(int row, int k){
    return row * 128 + ((((k >> 3) ^ (row & 15)) << 3) | (k & 7));
}

__global__ __launch_bounds__(256, 1) void sap_fused(
    const float* __restrict__ inp, const void* __restrict__ maskp,
    const float* __restrict__ pos, const float* __restrict__ W1,
    const float* __restrict__ W2, const float* __restrict__ Wout,
    float* __restrict__ out)
{
    __shared__ unsigned short s_w1t[128 * 128];  // W1^T [a][k] bf16, swizzled (32 KB)
    __shared__ unsigned short s_xp [LP  * 128];  // xp [l][k] bf16, swizzled (52 KB)
    __shared__ unsigned short s_hid[128 * LP ];  // tanh(hidden)^T [a][l] bf16 (52 KB)
    __shared__ float s_att [4 * LP];
    __shared__ float s_w2  [128 * 4];
    __shared__ float s_pool[512];
    __shared__ float s_red [256];
    __shared__ float s_mask[LP];
    __shared__ int   s_flag;

    const int t = threadIdx.x;
    const int b = blockIdx.x;

    // ---- detect mask dtype (bool-bytes vs int32 vs f32) deterministically ----
    if (t == 0){
        const unsigned* mw = (const unsigned*)maskp;
        int fi = 1, ff = 1;
        for (int i = 0; i < 64; ++i){
            unsigned w = mw[i];
            if (w > 1u) fi = 0;
            if (w != 0u && w != 0x3F800000u) ff = 0;
        }
        s_flag = fi ? 0 : (ff ? 2 : 1);
    }
    __syncthreads();
    const int flag = s_flag;

    // ---- stage mask + W2 ----
    for (int l = t; l < LP; l += 256){
        float m = 0.f;
        if (l < Ln){
            int mv;
            if (flag == 0)      mv = ((const int*)maskp)[b * Ln + l] != 0;
            else if (flag == 1) mv = ((const unsigned char*)maskp)[b * Ln + l] != 0;
            else                mv = ((const float*)maskp)[b * Ln + l] != 0.f;
            m = mv ? 1.f : 0.f;
        }
        s_mask[l] = m;
    }
    for (int i = t; i < 512; i += 256) s_w2[i] = W2[i];
    __syncthreads();

    // ---- stage xp = mask*x + pos (bf16, swizzled) + zero pad rows; stage W1^T ----
    {
        const float4* in4 = (const float4*)(inp + (size_t)b * (Ln * En));
        const float4* p4  = (const float4*)pos;
        for (int it = 0; it < 25; ++it){
            int idx = it * 256 + t;            // float4 index; 32 per row
            int l = idx >> 5;
            float m = s_mask[l];
            float4 a = in4[idx];
            float4 p = p4[idx];
            float x0 = a.x * m + p.x, x1 = a.y * m + p.y;
            float x2 = a.z * m + p.z, x3 = a.w * m + p.w;
            unsigned v0 = (unsigned)f2bf(x0) | ((unsigned)f2bf(x1) << 16);
            unsigned v1 = (unsigned)f2bf(x2) | ((unsigned)f2bf(x3) << 16);
            int k = (idx & 31) * 4;
            *(uint2*)&s_xp[swz(l, k)] = make_uint2(v0, v1);
        }
        { // zero rows 200..207
            int row = Ln + (t >> 5);
            int k = (t & 31) * 4;
            *(uint2*)&s_xp[swz(row, k)] = make_uint2(0u, 0u);
        }
        const float4* w14 = (const float4*)W1;
        for (int it = 0; it < 16; ++it){
            int idx = it * 256 + t;            // W1[k][c..c+3]
            int k = idx >> 5;
            int c = (idx & 31) * 4;
            float4 wv = w14[idx];
            s_w1t[swz(c + 0, k)] = f2bf(wv.x);
            s_w1t[swz(c + 1, k)] = f2bf(wv.y);
            s_w1t[swz(c + 2, k)] = f2bf(wv.z);
            s_w1t[swz(c + 3, k)] = f2bf(wv.w);
        }
    }
    __syncthreads();

    // ---- MFMA GEMM: hid_t[a][l] = tanh( sum_k W1[k][a] * xp[l][k] ) ----
    {
        const int lane = t & 63, w = t >> 6;
        const int c = lane & 15, q = lane >> 4;
        bf16x8 af[2][4];
        #pragma unroll
        for (int at = 0; at < 2; ++at){
            int arow = (w * 2 + at) * 16 + c;
            #pragma unroll
            for (int ks = 0; ks < 4; ++ks){
                int g = (ks * 4 + q) ^ c;
                af[at][ks] = *(bf16x8*)&s_w1t[arow * 128 + (g << 3)];
            }
        }
        for (int lt = 0; lt < 13; ++lt){
            int brow = lt * 16 + c;
            bf16x8 bfr[4];
            #pragma unroll
            for (int ks = 0; ks < 4; ++ks){
                int g = (ks * 4 + q) ^ c;
                bfr[ks] = *(bf16x8*)&s_xp[brow * 128 + (g << 3)];
            }
            f32x4 acc0 = {0.f,0.f,0.f,0.f}, acc1 = {0.f,0.f,0.f,0.f};
            #pragma unroll
            for (int ks = 0; ks < 4; ++ks){
                acc0 = __builtin_amdgcn_mfma_f32_16x16x32_bf16(af[0][ks], bfr[ks], acc0, 0, 0, 0);
                acc1 = __builtin_amdgcn_mfma_f32_16x16x32_bf16(af[1][ks], bfr[ks], acc1, 0, 0, 0);
            }
            int lidx = lt * 16 + c;
            #pragma unroll
            for (int v = 0; v < 4; ++v){
                int a0 = (w * 2 + 0) * 16 + q * 4 + v;
                int a1 = (w * 2 + 1) * 16 + q * 4 + v;
                s_hid[a0 * LP + lidx] = f2bf(tanh_fast(acc0[v]));
                s_hid[a1 * LP + lidx] = f2bf(tanh_fast(acc1[v]));
            }
        }
    }
    __syncthreads();

    // ---- att_raw[h][l] = sum_a hid_t[a][l] * W2[a][h] ----
    if (t < LP){
        int l = t;
        float a0 = 0.f, a1 = 0.f, a2 = 0.f, a3 = 0.f;
        #pragma unroll 2
        for (int a = 0; a < 128; ++a){
            float hv = bf2f(s_hid[a * LP + l]);
            float4 w = *(float4*)&s_w2[a * 4];
            a0 += hv * w.x; a1 += hv * w.y; a2 += hv * w.z; a3 += hv * w.w;
        }
        s_att[0 * LP + l] = a0; s_att[1 * LP + l] = a1;
        s_att[2 * LP + l] = a2; s_att[3 * LP + l] = a3;
    }
    __syncthreads();

    // ---- masked softmax over l, wave h ----
    {
        const int lane = t & 63, h = t >> 6;
        float v[4]; bool ok[4]; float mx = -FLT_MAX;
        #pragma unroll
        for (int i = 0; i < 4; ++i){
            int l = lane + i * 64;
            ok[i] = (l < Ln) && (s_mask[l] > 0.5f);
            v[i]  = ok[i] ? s_att[h * LP + l] : -FLT_MAX;
            mx = fmaxf(mx, v[i]);
        }
        for (int s = 32; s; s >>= 1) mx = fmaxf(mx, __shfl_xor(mx, s, 64));
        float e[4]; float sum = 0.f;
        #pragma unroll
        for (int i = 0; i < 4; ++i){
            e[i] = ok[i] ? __expf(v[i] - mx) : 0.f;
            sum += e[i];
        }
        for (int s = 32; s; s >>= 1) sum += __shfl_xor(sum, s, 64);
        float inv = 1.f / sum;
        #pragma unroll
        for (int i = 0; i < 4; ++i){
            int l = lane + i * 64;
            if (l < LP) s_att[h * LP + l] = e[i] * inv;
        }
    }
    __syncthreads();

    // ---- pooled[h][e] = sum_l att[h][l] * (xp[l][e] - pos[l][e]) ----
    {
        int e = t & 127, h2 = t >> 7;      // h2 handles h2 and h2+2
        float acc0 = 0.f, acc1 = 0.f;
        #pragma unroll 4
        for (int l = 0; l < Ln; ++l){
            float xv = bf2f(s_xp[swz(l, e)]) - pos[l * En + e];
            acc0 += s_att[h2 * LP + l] * xv;
            acc1 += s_att[(h2 + 2) * LP + l] * xv;
        }
        s_pool[h2 * En + e]       = acc0;
        s_pool[(h2 + 2) * En + e] = acc1;
    }
    __syncthreads();

    // ---- out[b][e] = sum_i pool[i] * Wout[i][e] ----
    {
        int e = t & 127, half = t >> 7;
        float acc = 0.f;
        const float* wo = Wout + (size_t)half * 256 * En + e;
        #pragma unroll 4
        for (int i = 0; i < 256; ++i)
            acc += s_pool[half * 256 + i] * wo[(size_t)i * En];
        s_red[t] = acc;
    }
    __syncthreads();
    if (t < 128) out[(size_t)b * En + t] = s_red[t] + s_red[t + 128];
}

extern "C" void kernel_launch(void* const* d_in, const int* in_sizes, int n_in,
                              void* d_out, int out_size, void* d_ws, size_t ws_size,
                              hipStream_t stream)
{
    const float* inp  = (const float*)d_in[0];
    const void*  mask = d_in[1];
    const float* pos  = (const float*)d_in[2];
    const float* W1   = (const float*)d_in[3];
    const float* W2   = (const float*)d_in[4];
    const float* Wout = (const float*)d_in[5];
    sap_fused<<<Bn, 256, 0, stream>>>(inp, mask, pos, W1, W2, Wout, (float*)d_out);
}

// Round 2
// 99.595 us; speedup vs baseline: 1.7387x; 1.7387x over previous
//
#include <hip/hip_runtime.h>
#include <cfloat>

#define Bn 1024
#define Ln 200
#define En 128
#define An 128
#define Hn 4
#define LP 208   // L padded to 13*16

using f32x4  = __attribute__((ext_vector_type(4))) float;
using bf16x8 = __attribute__((ext_vector_type(8))) short;

__device__ __forceinline__ unsigned short f2bf(float f){
    unsigned u = __builtin_bit_cast(unsigned, f);
    u = (u + 0x7FFFu + ((u >> 16) & 1u)) >> 16;   // RNE
    return (unsigned short)u;
}
__device__ __forceinline__ float bf2f(unsigned short s){
    unsigned u = ((unsigned)s) << 16;
    return __builtin_bit_cast(float, u);
}
__device__ __forceinline__ float tanh_fast(float x){
    x = fminf(fmaxf(x, -12.f), 12.f);
    float e = __expf(2.f * x);
    return 1.f - 2.f / (e + 1.f);
}
// swizzled short-index for a [row][128] bf16 LDS array (256B rows, 16B granule XOR)
__device__ __forceinline__ int swz(int row, int k){
    return row * 128 + ((((k >> 3) ^ (row & 15)) << 3) | (k & 7));
}

__global__ __launch_bounds__(512, 4) void sap_fused(
    const float* __restrict__ inp, const void* __restrict__ maskp,
    const float* __restrict__ pos, const float* __restrict__ W1,
    const float* __restrict__ W2, const float* __restrict__ Wout,
    float* __restrict__ out)
{
    __shared__ unsigned short s_xp [LP * 128];   // xp [l][k] bf16, swizzled (53.2 KB)
    __shared__ float s_att [4 * LP];             // 3.3 KB
    __shared__ float s_mask[LP];                 // 832 B
    __shared__ float s_pool[512];                // 2 KB
    __shared__ float s_red [512];                // 2 KB
    __shared__ int   s_flag;

    const int t = threadIdx.x;
    const int b = blockIdx.x;
    const int lane = t & 63, w = t >> 6;         // 8 waves
    const int c = lane & 15, q = lane >> 4;

    // ---- detect mask dtype (int32 vs bool-bytes vs f32) deterministically ----
    if (t == 0){
        const unsigned* mw = (const unsigned*)maskp;
        int fi = 1, ff = 1;
        for (int i = 0; i < 64; ++i){
            unsigned word = mw[i];
            if (word > 1u) fi = 0;
            if (word != 0u && word != 0x3F800000u) ff = 0;
        }
        s_flag = fi ? 0 : (ff ? 2 : 1);
    }

    // ---- W1 MFMA fragments + W2 straight from global into registers (L2-hot) ----
    // A-operand tile: wave w owns a-rows [w*16, w*16+16). Lane (q,c):
    // af[ks][j] = W1^T[w*16+c][ks*32+q*8+j] = W1[(ks*32+q*8+j)][w*16+c]
    bf16x8 af[4];
    {
        const int arow = w * 16 + c;
        #pragma unroll
        for (int ks = 0; ks < 4; ++ks)
            #pragma unroll
            for (int j = 0; j < 8; ++j)
                af[ks][j] = (short)f2bf(W1[(ks * 32 + q * 8 + j) * An + arow]);
    }
    float w2a[4][4];   // w2a[v][h] = W2[w*16+q*4+v][h]
    #pragma unroll
    for (int v = 0; v < 4; ++v){
        float4 wv = *(const float4*)&W2[(w * 16 + q * 4 + v) * Hn];
        w2a[v][0] = wv.x; w2a[v][1] = wv.y; w2a[v][2] = wv.z; w2a[v][3] = wv.w;
    }

    __syncthreads();                       // s_flag ready
    const int flag = s_flag;

    // ---- stage mask, zero att accumulators ----
    for (int l = t; l < LP; l += 512){
        float m = 0.f;
        if (l < Ln){
            int mv;
            if (flag == 0)      mv = ((const int*)maskp)[b * Ln + l] != 0;
            else if (flag == 1) mv = ((const unsigned char*)maskp)[b * Ln + l] != 0;
            else                mv = ((const float*)maskp)[b * Ln + l] != 0.f;
            m = mv ? 1.f : 0.f;
        }
        s_mask[l] = m;
    }
    for (int i = t; i < 4 * LP; i += 512) s_att[i] = 0.f;
    __syncthreads();                       // s_mask ready

    // ---- stage xp = mask*x + pos (bf16, swizzled), zero pad rows ----
    {
        const float4* in4 = (const float4*)(inp + (size_t)b * (Ln * En));
        const float4* p4  = (const float4*)pos;
        #pragma unroll
        for (int it = 0; it < 13; ++it){
            int idx = it * 512 + t;        // float4 slot, 32 per row, 6656 total
            int l = idx >> 5;
            int k = (idx & 31) * 4;
            uint2 val;
            if (idx < 6400){
                float m = s_mask[l];
                float4 a = in4[idx];
                float4 p = p4[idx];
                float x0 = a.x * m + p.x, x1 = a.y * m + p.y;
                float x2 = a.z * m + p.z, x3 = a.w * m + p.w;
                val = make_uint2((unsigned)f2bf(x0) | ((unsigned)f2bf(x1) << 16),
                                 (unsigned)f2bf(x2) | ((unsigned)f2bf(x3) << 16));
            } else {
                val = make_uint2(0u, 0u);
            }
            *(uint2*)&s_xp[swz(l, k)] = val;
        }
    }
    __syncthreads();

    // ---- MFMA: hid[a][l] = tanh(sum_k W1[k][a] xp[l][k]); fused att accumulate ----
    for (int lt = 0; lt < 13; ++lt){
        int brow = lt * 16 + c;
        bf16x8 bfr[4];
        #pragma unroll
        for (int ks = 0; ks < 4; ++ks){
            int g = (ks * 4 + q) ^ c;
            bfr[ks] = *(bf16x8*)&s_xp[brow * 128 + (g << 3)];
        }
        f32x4 acc = {0.f, 0.f, 0.f, 0.f};
        #pragma unroll
        for (int ks = 0; ks < 4; ++ks)
            acc = __builtin_amdgcn_mfma_f32_16x16x32_bf16(af[ks], bfr[ks], acc, 0, 0, 0);
        // D layout: l = lt*16 + (lane&15), a = w*16 + q*4 + v
        float hv[4];
        #pragma unroll
        for (int v = 0; v < 4; ++v) hv[v] = tanh_fast(acc[v]);
        #pragma unroll
        for (int h = 0; h < 4; ++h){
            float contrib = hv[0] * w2a[0][h] + hv[1] * w2a[1][h]
                          + hv[2] * w2a[2][h] + hv[3] * w2a[3][h];
            contrib += __shfl_xor(contrib, 16, 64);   // reduce over q
            contrib += __shfl_xor(contrib, 32, 64);
            if (lane < 16)
                atomicAdd(&s_att[h * LP + lt * 16 + lane], contrib);
        }
    }
    __syncthreads();

    // ---- masked softmax over l (waves 0-3, one per head) ----
    if (t < 256){
        const int sl = t & 63, h = t >> 6;
        float v[4]; bool ok[4]; float mx = -FLT_MAX;
        #pragma unroll
        for (int i = 0; i < 4; ++i){
            int l = sl + i * 64;
            ok[i] = (l < Ln) && (s_mask[l] > 0.5f);
            v[i]  = ok[i] ? s_att[h * LP + l] : -FLT_MAX;
            mx = fmaxf(mx, v[i]);
        }
        for (int s = 32; s; s >>= 1) mx = fmaxf(mx, __shfl_xor(mx, s, 64));
        float e[4]; float sum = 0.f;
        #pragma unroll
        for (int i = 0; i < 4; ++i){
            e[i] = ok[i] ? __expf(v[i] - mx) : 0.f;
            sum += e[i];
        }
        for (int s = 32; s; s >>= 1) sum += __shfl_xor(sum, s, 64);
        float inv = 1.f / sum;
        #pragma unroll
        for (int i = 0; i < 4; ++i){
            int l = sl + i * 64;
            if (l < LP) s_att[h * LP + l] = e[i] * inv;
        }
    }
    __syncthreads();

    // ---- pooled[h][e] = sum_l att[h][l] * (xp[l][e] - pos[l][e]) ----
    {
        int h = t >> 7, e = t & 127;
        float acc = 0.f;
        #pragma unroll 4
        for (int l = 0; l < Ln; ++l){
            float xv = bf2f(s_xp[swz(l, e)]) - pos[l * En + e];
            acc += s_att[h * LP + l] * xv;
        }
        s_pool[h * En + e] = acc;
    }
    __syncthreads();

    // ---- out[b][e] = sum_i pool[i] * Wout[i][e], 4-way split over i ----
    {
        int qt = t >> 7, e = t & 127;
        float acc = 0.f;
        const float* wo = Wout + (size_t)(qt * 128) * En + e;
        #pragma unroll 4
        for (int i = 0; i < 128; ++i)
            acc += s_pool[qt * 128 + i] * wo[(size_t)i * En];
        s_red[t] = acc;
    }
    __syncthreads();
    if (t < 128)
        out[(size_t)b * En + t] = s_red[t] + s_red[t + 128] + s_red[t + 256] + s_red[t + 384];
}

extern "C" void kernel_launch(void* const* d_in, const int* in_sizes, int n_in,
                              void* d_out, int out_size, void* d_ws, size_t ws_size,
                              hipStream_t stream)
{
    const float* inp  = (const float*)d_in[0];
    const void*  mask = d_in[1];
    const float* pos  = (const float*)d_in[2];
    const float* W1   = (const float*)d_in[3];
    const float* W2   = (const float*)d_in[4];
    const float* Wout = (const float*)d_in[5];
    sap_fused<<<Bn, 512, 0, stream>>>(inp, mask, pos, W1, W2, Wout, (float*)d_out);
}